// Round 13
// baseline (566.653 us; speedup 1.0000x reference)
//
#include <hip/hip_runtime.h>

constexpr int Nn = 50000;
constexpr int Ee = 800000;
constexpr int Qq = 2000000;
constexpr int Gg = 64;
constexpr int Hh = 128;
constexpr int NB64 = (Nn + 63) / 64;
constexpr int NSCB = (Nn + 1023) / 1024;   // 49 scan blocks
constexpr int NBUK = Nn / 16;              // 3125 edge buckets (16 nodes each)

typedef short bf16x8 __attribute__((ext_vector_type(8)));
typedef float f32x4  __attribute__((ext_vector_type(4)));

__device__ __forceinline__ unsigned short f2bf(float f) {
    unsigned u = __builtin_bit_cast(unsigned, f);
    u += 0x7FFFu + ((u >> 16) & 1u);
    return (unsigned short)(u >> 16);
}
__device__ __forceinline__ float bf2f(unsigned short s) {
    unsigned u = ((unsigned)s) << 16;
    return __builtin_bit_cast(float, u);
}

// ---------------- fused histograms (edges by dst, quads by k_idx) ----------------
__global__ void k_hist2(const int* __restrict__ dst, const int* __restrict__ kidx,
                        int* __restrict__ hist_e, int* __restrict__ hist_q) {
    int i = blockIdx.x * blockDim.x + threadIdx.x;
    if (i < Ee) atomicAdd(&hist_e[dst[i]], 1);
    if (i < Qq) { int v = kidx[i]; if (v < Nn) atomicAdd(&hist_q[v], 1); }
}

// ---------------- hierarchical exclusive scan, 2 arrays via blockIdx.y ----------------
__global__ __launch_bounds__(1024) void k_scanA2(const int* __restrict__ he,
                                                 const int* __restrict__ hq,
                                                 int* __restrict__ ce, int* __restrict__ cq,
                                                 int* __restrict__ bs) {
    __shared__ int s[1024];
    const int* h = blockIdx.y ? hq : he;
    int* c = blockIdx.y ? cq : ce;
    int* b = bs + blockIdx.y * 64;
    const int tid = threadIdx.x;
    int i = blockIdx.x * 1024 + tid;
    int v = (i < Nn) ? h[i] : 0;
    s[tid] = v;
    __syncthreads();
    for (int off = 1; off < 1024; off <<= 1) {
        int t = (tid >= off) ? s[tid - off] : 0;
        __syncthreads();
        s[tid] += t;
        __syncthreads();
    }
    if (i < Nn) c[i] = s[tid] - v;
    if (tid == 1023) b[blockIdx.x] = s[1023];
}
__global__ void k_scanB2(int* __restrict__ bs) {
    __shared__ int s[64];
    int* b = bs + blockIdx.x * 64;
    const int tid = threadIdx.x;
    int v = (tid < NSCB) ? b[tid] : 0;
    s[tid] = v;
    __syncthreads();
    for (int off = 1; off < 64; off <<= 1) {
        int t = (tid >= off) ? s[tid - off] : 0;
        __syncthreads();
        s[tid] += t;
        __syncthreads();
    }
    if (tid < NSCB) b[tid] = s[tid] - v;
}
__global__ __launch_bounds__(1024) void k_scanC2(int* __restrict__ ce, int* __restrict__ cq,
                                                 const int* __restrict__ bs) {
    int* c = blockIdx.y ? cq : ce;
    const int* b = bs + blockIdx.y * 64;
    int i = blockIdx.x * 1024 + threadIdx.x;
    if (i < Nn) c[i] += b[blockIdx.x];
}

// ---------------- bucket cursors = CSR offsets of each bucket's first node ----------
__global__ void k_bukinit(const int* __restrict__ cur_e, int* __restrict__ ebcur) {
    int b = blockIdx.x * blockDim.x + threadIdx.x;
    if (b < NBUK) ebcur[b] = cur_e[b * 16];
}

// ---------------- fused scatter: edges -> bucket stage (packed 4B); quads -> qrec ----
__global__ void k_scatter_both(const int* __restrict__ dst, const int* __restrict__ src,
                               const int* __restrict__ kidx, const int* __restrict__ lidx,
                               const float* __restrict__ cbf, const float* __restrict__ sbf,
                               int* __restrict__ ebcur, int* __restrict__ cur_q,
                               unsigned* __restrict__ estage,
                               unsigned short* __restrict__ qrec) {
    int i = blockIdx.x * blockDim.x + threadIdx.x;
    if (i < Ee) {
        int d = dst[i];
        int p = atomicAdd(&ebcur[d >> 4], 1);
        estage[p] = (unsigned)src[i] | ((unsigned)(d & 15) << 16);
    }
    if (i < Qq) {
        int v = kidx[i];
        if (v < Nn) {
            int p = atomicAdd(&cur_q[v], 1);
            unsigned short rec[16];
            ((int*)rec)[0] = lidx[i];
#pragma unroll
            for (int k = 0; k < 6; ++k) rec[2 + k] = f2bf(cbf[(size_t)i * 6 + k]);
#pragma unroll
            for (int k = 0; k < 6; ++k) rec[8 + k] = f2bf(sbf[(size_t)i * 6 + k]);
            rec[14] = 0; rec[15] = 0;
            *(uint4*)&qrec[(size_t)p * 16]     = *(uint4*)&rec[0];
            *(uint4*)&qrec[(size_t)p * 16 + 8] = *(uint4*)&rec[8];
        }
    }
}

// ---------------- pass 2: bucket stage -> final CSR srcs (L2-local, no amplification) -
// cur_e (row_beg) is NEVER mutated; per-node positions resolved via LDS cursors.
__global__ __launch_bounds__(256) void k_finalize(
    const unsigned* __restrict__ estage, const int* __restrict__ cur_e,
    const int* __restrict__ hist_e, int* __restrict__ srcs) {
    __shared__ int lcur[16];
    const int b = blockIdx.x;
    const int tid = threadIdx.x;
    const int n0 = b * 16;
    if (tid < 16) lcur[tid] = cur_e[n0 + tid];
    __syncthreads();
    const int beg = cur_e[n0];
    const int end = cur_e[n0 + 15] + hist_e[n0 + 15];
    for (int i = beg + tid; i < end; i += 256) {
        unsigned pk = estage[i];
        int nd = (pk >> 16) & 15;
        int p = atomicAdd(&lcur[nd], 1);
        srcs[p] = (int)(pk & 0xFFFFu);
    }
}

// ---------------- fused per-layer weight transpose to bf16 ----------------
// per-layer slice: [0)Wq1t[128][128] [16384)Wp2t[128][32] [20480)We1bt[128][128]
// [36864)We2at[128][256] [69632)We2bt[128][128] [86016)Wnat[128][256] [118784)Wnbt[128][128]
__global__ void k_wtall(const float* __restrict__ We1a0, const float* __restrict__ We1b0,
                        const float* __restrict__ We2a0, const float* __restrict__ We2b0,
                        const float* __restrict__ Wna0,  const float* __restrict__ Wnb0,
                        unsigned short* __restrict__ wbuf) {
    int idx = blockIdx.x * blockDim.x + threadIdx.x;
    if (idx >= 135168) return;
    const int p = blockIdx.y;
    const float* We1a = We1a0 + (size_t)p * 146 * 128;
    const float* We1b = We1b0 + (size_t)p * 128 * 128;
    const float* We2a = We2a0 + (size_t)p * 256 * 128;
    const float* We2b = We2b0 + (size_t)p * 128 * 128;
    const float* Wna  = Wna0  + (size_t)p * 256 * 128;
    const float* Wnb  = Wnb0  + (size_t)p * 128 * 128;
    unsigned short* base = wbuf + (size_t)p * 135168;
    const float* src; int K, Kp, loc;
    if (idx < 16384)       { src = We1a;             K = 128; Kp = 128; loc = idx; }
    else if (idx < 20480)  { src = We1a + 128 * 128; K = 6;   Kp = 32;  loc = idx - 16384; }
    else if (idx < 36864)  { src = We1b;             K = 128; Kp = 128; loc = idx - 20480; }
    else if (idx < 69632)  { src = We2a;             K = 256; Kp = 256; loc = idx - 36864; }
    else if (idx < 86016)  { src = We2b;             K = 128; Kp = 128; loc = idx - 69632; }
    else if (idx < 118784) { src = Wna;              K = 256; Kp = 256; loc = idx - 86016; }
    else                   { src = Wnb;              K = 128; Kp = 128; loc = idx - 118784; }
    int n = loc / Kp, k = loc - n * Kp;
    base[idx] = (k < K) ? f2bf(src[(size_t)k * 128 + n]) : (unsigned short)0;
}

// ---------------- GEMM building blocks ----------------
__device__ __forceinline__ void zacc(f32x4 acc[4][2]) {
#pragma unroll
    for (int rt = 0; rt < 4; ++rt)
#pragma unroll
        for (int ct = 0; ct < 2; ++ct)
            acc[rt][ct] = (f32x4){0.f, 0.f, 0.f, 0.f};
}

template<int KK, int SA, int KP>
__device__ __forceinline__ void gemm64(const unsigned short* A,
                                       const unsigned short* __restrict__ Wt,
                                       int k_off, f32x4 acc[4][2]) {
    const int tid = threadIdx.x;
    const int lane = tid & 63;
    const int nb = (tid >> 6) * 32;
    const int rA = lane & 15;
    const int kg = lane >> 4;
#pragma unroll
    for (int ks = 0; ks < KK / 32; ++ks) {
        const int ka = ks * 32 + kg * 8;
        const int kb = k_off + ka;
        bf16x8 b0 = *(const bf16x8*)&Wt[(size_t)(nb + rA) * KP + kb];
        bf16x8 b1 = *(const bf16x8*)&Wt[(size_t)(nb + 16 + rA) * KP + kb];
#pragma unroll
        for (int rt = 0; rt < 4; ++rt) {
            bf16x8 a = *(const bf16x8*)&A[(rt * 16 + rA) * SA + ka];
            acc[rt][0] = __builtin_amdgcn_mfma_f32_16x16x32_bf16(a, b0, acc[rt][0], 0, 0, 0);
            acc[rt][1] = __builtin_amdgcn_mfma_f32_16x16x32_bf16(a, b1, acc[rt][1], 0, 0, 0);
        }
    }
}

__device__ __forceinline__ void store_acc(const f32x4 acc[4][2], unsigned short* out,
                                          int n0, int nmax) {
    const int tid = threadIdx.x;
    const int lane = tid & 63;
    const int nb = (tid >> 6) * 32;
    const int rA = lane & 15, kg = lane >> 4;
#pragma unroll
    for (int rt = 0; rt < 4; ++rt)
#pragma unroll
        for (int ct = 0; ct < 2; ++ct) {
            int col = nb + ct * 16 + rA;
#pragma unroll
            for (int i = 0; i < 4; ++i) {
                int n = n0 + rt * 16 + kg * 4 + i;
                if (n < nmax) out[(size_t)n * 128 + col] = f2bf(acc[rt][ct][i]);
            }
        }
}

// ---------------- k_pre0: hb=bf16(x); P1=h*Wq1(l0); Z1=h*We2a(l0)[:128]; P2(l0..l2) -----
__global__ __launch_bounds__(256) void k_pre0(
    const float* __restrict__ x, const float* __restrict__ rbf,
    const unsigned short* __restrict__ wbuf,
    unsigned short* __restrict__ hb,
    unsigned short* __restrict__ P1, unsigned short* __restrict__ Z1,
    unsigned short* __restrict__ P2all)
{
    __shared__ unsigned short TA[64 * 136];
    const int m0 = blockIdx.x * 64;
    const int tid = threadIdx.x;
    for (int i = tid; i < 64 * 32; i += 256) {
        int row = i >> 5, c = i & 31;
        int n = m0 + row;
        int nc = min(n, Nn - 1);
        float4 v = *(const float4*)&x[(size_t)nc * 128 + c * 4];
        ushort4 o;
        o.x = f2bf(v.x); o.y = f2bf(v.y); o.z = f2bf(v.z); o.w = f2bf(v.w);
        *(ushort4*)&TA[row * 136 + c * 4] = o;
        if (n < Nn) *(ushort4*)&hb[(size_t)n * 128 + c * 4] = o;
    }
    __syncthreads();
    f32x4 acc[4][2];
    zacc(acc);
    gemm64<128, 136, 128>(TA, wbuf, 0, acc);
    store_acc(acc, P1, m0, Nn);
    zacc(acc);
    gemm64<128, 136, 256>(TA, wbuf + 36864, 0, acc);
    store_acc(acc, Z1, m0, Nn);
    __syncthreads();
    for (int i = tid; i < 64 * 32; i += 256) {
        int row = i >> 5, c = i & 31;
        int nc = min(m0 + row, Nn - 1);
        float v = (c < 6) ? rbf[(size_t)nc * 6 + c] : 0.f;
        TA[row * 136 + c] = f2bf(v);
    }
    __syncthreads();
    for (int p = 0; p < 3; ++p) {
        zacc(acc);
        gemm64<32, 136, 32>(TA, wbuf + (size_t)p * 135168 + 16384, 0, acc);
        store_acc(acc, P2all + (size_t)p * Nn * 128, m0, Nn);
    }
}

// ---------------- k_quadagg: CSR owner-computes quad reduction (zero atomics) --------
__global__ __launch_bounds__(256) void k_quadagg(
    const unsigned short* __restrict__ P1, const unsigned short* __restrict__ P2,
    const unsigned short* __restrict__ qrec,
    const int* __restrict__ rowend, const int* __restrict__ rowcnt,
    const float* __restrict__ We1a_raw, const float* __restrict__ b_e1a,
    unsigned short* __restrict__ Rb)
{
    __shared__ float W34[12 * 128];
    __shared__ float bia[128];
    const int tid = threadIdx.x;
    for (int i = tid; i < 12 * 128; i += 256) W34[i] = We1a_raw[134 * 128 + i];
    if (tid < 128) bia[tid] = b_e1a[tid];
    __syncthreads();
    const int nd = tid >> 4;
    const int c0 = (tid & 15) * 8;
    const int n = blockIdx.x * 16 + nd;
    const int end = rowend[n];
    const int beg = end - rowcnt[n];
    float base[8];
    {
        uint4 p2v = *(const uint4*)&P2[(size_t)n * 128 + c0];
        const unsigned short* pp = (const unsigned short*)&p2v;
#pragma unroll
        for (int k = 0; k < 8; ++k) base[k] = bia[c0 + k] + bf2f(pp[k]);
    }
    float acc[8];
#pragma unroll
    for (int k = 0; k < 8; ++k) acc[k] = 0.f;
    for (int e = beg; e < end; ++e) {
        uint4 r0 = *(const uint4*)&qrec[(size_t)e * 16];
        uint4 r1 = *(const uint4*)&qrec[(size_t)e * 16 + 8];
        int l = ((const int*)&r0)[0];
        uint4 a = *(const uint4*)&P1[(size_t)l * 128 + c0];
        const unsigned short* q0 = (const unsigned short*)&r0;
        const unsigned short* q1 = (const unsigned short*)&r1;
        float qv[12] = {bf2f(q0[2]), bf2f(q0[3]), bf2f(q0[4]), bf2f(q0[5]),
                        bf2f(q0[6]), bf2f(q0[7]), bf2f(q1[0]), bf2f(q1[1]),
                        bf2f(q1[2]), bf2f(q1[3]), bf2f(q1[4]), bf2f(q1[5])};
        const unsigned short* ap = (const unsigned short*)&a;
        float t[8];
#pragma unroll
        for (int k = 0; k < 8; ++k) t[k] = base[k] + bf2f(ap[k]);
#pragma unroll
        for (int kk = 0; kk < 12; ++kk) {
            float q_ = qv[kk];
#pragma unroll
            for (int k = 0; k < 8; ++k)
                t[k] = fmaf(q_, W34[kk * 128 + c0 + k], t[k]);
        }
#pragma unroll
        for (int k = 0; k < 8; ++k) acc[k] += fmaxf(t[k], 0.f);
    }
    unsigned short ov[8];
#pragma unroll
    for (int k = 0; k < 8; ++k) ov[k] = f2bf(acc[k]);
    *(uint4*)&Rb[(size_t)n * 128 + c0] = *(uint4*)ov;
}

// ---------------- k_edgeagg: CSR owner-computes edge reduction, 4-way ILP --------
// rowbeg = cur_e (row_beg, immutable); end = beg + cnt.
__global__ __launch_bounds__(256) void k_edgeagg(
    const unsigned short* __restrict__ Z1, const unsigned short* __restrict__ Z2,
    const int* __restrict__ srcs,
    const int* __restrict__ rowbeg, const int* __restrict__ rowcnt,
    const float* __restrict__ b_e2a,
    unsigned short* __restrict__ Rb)
{
    const int tid = threadIdx.x;
    const int nd = tid >> 4;
    const int c0 = (tid & 15) * 8;
    const int n = blockIdx.x * 16 + nd;
    const int beg = rowbeg[n];
    const int end = beg + rowcnt[n];
    float z2b[8];
    {
        uint4 zv = *(const uint4*)&Z2[(size_t)n * 128 + c0];
        const unsigned short* zp = (const unsigned short*)&zv;
        float4 b0 = *(const float4*)&b_e2a[c0];
        float4 b1 = *(const float4*)&b_e2a[c0 + 4];
        z2b[0] = b0.x + bf2f(zp[0]); z2b[1] = b0.y + bf2f(zp[1]);
        z2b[2] = b0.z + bf2f(zp[2]); z2b[3] = b0.w + bf2f(zp[3]);
        z2b[4] = b1.x + bf2f(zp[4]); z2b[5] = b1.y + bf2f(zp[5]);
        z2b[6] = b1.z + bf2f(zp[6]); z2b[7] = b1.w + bf2f(zp[7]);
    }
    float acc[8];
#pragma unroll
    for (int k = 0; k < 8; ++k) acc[k] = 0.f;
    int e = beg;
    for (; e + 4 <= end; e += 4) {           // 4-way ILP on the gather
        int s0 = srcs[e], s1 = srcs[e + 1], s2 = srcs[e + 2], s3 = srcs[e + 3];
        uint4 a0 = *(const uint4*)&Z1[(size_t)s0 * 128 + c0];
        uint4 a1 = *(const uint4*)&Z1[(size_t)s1 * 128 + c0];
        uint4 a2 = *(const uint4*)&Z1[(size_t)s2 * 128 + c0];
        uint4 a3 = *(const uint4*)&Z1[(size_t)s3 * 128 + c0];
        const unsigned short* p0 = (const unsigned short*)&a0;
        const unsigned short* p1 = (const unsigned short*)&a1;
        const unsigned short* p2 = (const unsigned short*)&a2;
        const unsigned short* p3 = (const unsigned short*)&a3;
#pragma unroll
        for (int k = 0; k < 8; ++k) acc[k] += fmaxf(z2b[k] + bf2f(p0[k]), 0.f);
#pragma unroll
        for (int k = 0; k < 8; ++k) acc[k] += fmaxf(z2b[k] + bf2f(p1[k]), 0.f);
#pragma unroll
        for (int k = 0; k < 8; ++k) acc[k] += fmaxf(z2b[k] + bf2f(p2[k]), 0.f);
#pragma unroll
        for (int k = 0; k < 8; ++k) acc[k] += fmaxf(z2b[k] + bf2f(p3[k]), 0.f);
    }
    for (; e + 2 <= end; e += 2) {
        int s0 = srcs[e], s1 = srcs[e + 1];
        uint4 a0 = *(const uint4*)&Z1[(size_t)s0 * 128 + c0];
        uint4 a1 = *(const uint4*)&Z1[(size_t)s1 * 128 + c0];
        const unsigned short* p0 = (const unsigned short*)&a0;
        const unsigned short* p1 = (const unsigned short*)&a1;
#pragma unroll
        for (int k = 0; k < 8; ++k) acc[k] += fmaxf(z2b[k] + bf2f(p0[k]), 0.f);
#pragma unroll
        for (int k = 0; k < 8; ++k) acc[k] += fmaxf(z2b[k] + bf2f(p1[k]), 0.f);
    }
    if (e < end) {
        int s0 = srcs[e];
        uint4 a0 = *(const uint4*)&Z1[(size_t)s0 * 128 + c0];
        const unsigned short* p0 = (const unsigned short*)&a0;
#pragma unroll
        for (int k = 0; k < 8; ++k) acc[k] += fmaxf(z2b[k] + bf2f(p0[k]), 0.f);
    }
    unsigned short ov[8];
#pragma unroll
    for (int k = 0; k < 8; ++k) ov[k] = f2bf(acc[k]);
    *(uint4*)&Rb[(size_t)n * 128 + c0] = *(uint4*)ov;
}

// ---------------- k_agg2z: T = Rq*We1b + cntq*b_e1b ; Z2 = T*We2a[128:256] ----------------
__global__ __launch_bounds__(256) void k_agg2z(
    const unsigned short* __restrict__ Rb, const int* __restrict__ cntq,
    const unsigned short* __restrict__ wb, const float* __restrict__ b_e1b,
    unsigned short* __restrict__ Z2)
{
    __shared__ unsigned short L[64 * 136];
    __shared__ int rc[64];
    const int m0 = blockIdx.x * 64;
    const int tid = threadIdx.x;
    const unsigned short* We1bt = wb + 20480;
    const unsigned short* We2at = wb + 36864;
    if (tid < 64) rc[tid] = (m0 + tid < Nn) ? cntq[m0 + tid] : 0;
    for (int i = tid; i < 64 * 16; i += 256) {
        int row = i >> 4, ch = i & 15;
        int n = min(m0 + row, Nn - 1);
        *(uint4*)&L[row * 136 + ch * 8] = *(const uint4*)&Rb[(size_t)n * 128 + ch * 8];
    }
    __syncthreads();
    f32x4 acc[4][2];
    zacc(acc);
    gemm64<128, 136, 128>(L, We1bt, 0, acc);
    __syncthreads();
    {
        const int lane = tid & 63;
        const int nb = (tid >> 6) * 32;
        const int rA = lane & 15, kg = lane >> 4;
#pragma unroll
        for (int rt = 0; rt < 4; ++rt)
#pragma unroll
            for (int ct = 0; ct < 2; ++ct) {
                int col = nb + ct * 16 + rA;
                float bias = b_e1b[col];
#pragma unroll
                for (int i = 0; i < 4; ++i) {
                    int row = rt * 16 + kg * 4 + i;
                    L[row * 136 + col] = f2bf(acc[rt][ct][i] + (float)rc[row] * bias);
                }
            }
    }
    __syncthreads();
    zacc(acc);
    gemm64<128, 136, 256>(L, We2at, 128, acc);
    store_acc(acc, Z2, m0, Nn);
}

// ---------------- k_nodeNew: in-place h update + next-layer P1/Z1 tail ----------------
template<int LAST>
__global__ __launch_bounds__(256) void k_nodeNew(
    const unsigned short* __restrict__ Rb, const int* __restrict__ deg,
    const unsigned short* __restrict__ wb,
    const float* __restrict__ b_e2b, const float* __restrict__ b_na,
    const float* __restrict__ b_nb,
    unsigned short* __restrict__ hb,
    const unsigned short* __restrict__ wbn,
    unsigned short* __restrict__ P1n, unsigned short* __restrict__ Z1n)
{
    __shared__ unsigned short L[64 * 136];
    __shared__ int rc[64];
    const int m0 = blockIdx.x * 64;
    const int tid = threadIdx.x;
    const unsigned short* We2bt = wb + 69632;
    const unsigned short* Wnat  = wb + 86016;
    const unsigned short* Wnbt  = wb + 118784;
    const int lane = tid & 63;
    const int nb = (tid >> 6) * 32;
    const int rA = lane & 15, kg = lane >> 4;
    if (tid < 64) rc[tid] = (m0 + tid < Nn) ? deg[m0 + tid] : 0;
    for (int i = tid; i < 64 * 16; i += 256) {
        int row = i >> 4, ch = i & 15;
        int n = min(m0 + row, Nn - 1);
        *(uint4*)&L[row * 136 + ch * 8] = *(const uint4*)&Rb[(size_t)n * 128 + ch * 8];
    }
    __syncthreads();
    f32x4 acc[4][2];
    zacc(acc);
    gemm64<128, 136, 128>(L, We2bt, 0, acc);     // U = Re*We2b
    __syncthreads();
#pragma unroll
    for (int rt = 0; rt < 4; ++rt)
#pragma unroll
        for (int ct = 0; ct < 2; ++ct) {
            int col = nb + ct * 16 + rA;
            float bias = b_e2b[col];
#pragma unroll
            for (int i = 0; i < 4; ++i) {
                int row = rt * 16 + kg * 4 + i;
                L[row * 136 + col] = f2bf(acc[rt][ct][i] + (float)rc[row] * bias);
            }
        }
    __syncthreads();
    f32x4 acc2[4][2];
    zacc(acc2);
    gemm64<128, 136, 256>(L, Wnat, 128, acc2);   // V = U*Wbot_n
    __syncthreads();
    for (int i = tid; i < 64 * 16; i += 256) {
        int row = i >> 4, ch = i & 15;
        int n = min(m0 + row, Nn - 1);
        *(uint4*)&L[row * 136 + ch * 8] = *(const uint4*)&hb[(size_t)n * 128 + ch * 8];
    }
    __syncthreads();
    gemm64<128, 136, 256>(L, Wnat, 0, acc2);     // V += h*Wtop_n
    __syncthreads();
#pragma unroll
    for (int rt = 0; rt < 4; ++rt)
#pragma unroll
        for (int ct = 0; ct < 2; ++ct) {
            int col = nb + ct * 16 + rA;
            float bias = b_na[col];
#pragma unroll
            for (int i = 0; i < 4; ++i) {
                int row = rt * 16 + kg * 4 + i;
                L[row * 136 + col] = f2bf(fmaxf(acc2[rt][ct][i] + bias, 0.f));
            }
        }
    __syncthreads();
    zacc(acc);
    gemm64<128, 136, 128>(L, Wnbt, 0, acc);      // h' = hidden*Wnb
    __syncthreads();                             // all L reads done before overwrite
#pragma unroll
    for (int rt = 0; rt < 4; ++rt)
#pragma unroll
        for (int ct = 0; ct < 2; ++ct) {
            int col = nb + ct * 16 + rA;
            float bias = b_nb[col];
#pragma unroll
            for (int i = 0; i < 4; ++i) {
                int row = rt * 16 + kg * 4 + i;
                int n = m0 + row;
                unsigned short hv = f2bf(acc[rt][ct][i] + bias);
                if (n < Nn) hb[(size_t)n * 128 + col] = hv;
                if (!LAST) L[row * 136 + col] = hv;
            }
        }
    if (!LAST) {
        __syncthreads();
        // tail: next layer's P1 = h'*Wq1n ; Z1 = h'*We2an[:128]  (h' already in LDS)
        zacc(acc);
        gemm64<128, 136, 128>(L, wbn, 0, acc);
        store_acc(acc, P1n, m0, Nn);
        zacc(acc);
        gemm64<128, 136, 256>(L, wbn + 36864, 0, acc);
        store_acc(acc, Z1n, m0, Nn);
    }
}

// ---------------- global mean pool: run-length segmented reduction ----------------
__global__ __launch_bounds__(256) void k_pool(const unsigned short* __restrict__ hb,
                                              const int* __restrict__ batch,
                                              float* __restrict__ pooled,
                                              float* __restrict__ cntg) {
    __shared__ int bseg[200];
    constexpr int CH = 196;
    const int start = blockIdx.x * CH;
    const int end = min(start + CH, Nn);
    if (start >= end) return;
    const int tid = threadIdx.x;
    for (int i = tid; i < end - start; i += 256) bseg[i] = batch[start + i];
    __syncthreads();
    const int j = tid & 127;
    const int rh = tid >> 7;
    float acc = 0.f, cacc = 0.f;
    int cur = -1;
    for (int n = start + rh; n < end; n += 2) {
        int g = bseg[n - start];
        if (g != cur) {
            if (cur >= 0) {
                atomicAdd(&pooled[cur * Hh + j], acc);
                if (j == 0) atomicAdd(&cntg[cur], cacc);
            }
            cur = g; acc = 0.f; cacc = 0.f;
        }
        acc += bf2f(hb[(size_t)n * Hh + j]);
        cacc += 1.f;
    }
    if (cur >= 0) {
        atomicAdd(&pooled[cur * Hh + j], acc);
        if (j == 0) atomicAdd(&cntg[cur], cacc);
    }
}

// ---------------- final per-graph MLP ----------------
__global__ __launch_bounds__(128) void k_final(
    const float* __restrict__ pooled, const float* __restrict__ cntg,
    const float* __restrict__ Woa, const float* __restrict__ boa,
    const float* __restrict__ Wob, const float* __restrict__ bob,
    float* __restrict__ out)
{
    __shared__ float p[128];
    __shared__ float t[128];
    __shared__ float red[128];
    const int g = blockIdx.x;
    const int j = threadIdx.x;
    float c = fmaxf(cntg[g], 1.f);
    p[j] = fmaxf(pooled[g * Hh + j] / c, 0.f);
    __syncthreads();
    float acc = boa[j];
    for (int d = 0; d < Hh; ++d) acc = fmaf(p[d], Woa[d * Hh + j], acc);
    t[j] = fmaxf(acc, 0.f);
    __syncthreads();
    red[j] = t[j] * Wob[j];
    __syncthreads();
    for (int s = 64; s > 0; s >>= 1) {
        if (j < s) red[j] += red[j + s];
        __syncthreads();
    }
    if (j == 0) out[g] = red[0] + bob[0];
}

extern "C" void kernel_launch(void* const* d_in, const int* in_sizes, int n_in,
                              void* d_out, int out_size, void* d_ws, size_t ws_size,
                              hipStream_t stream) {
    const float* x     = (const float*)d_in[0];
    const float* rbf   = (const float*)d_in[1];
    const float* cbf   = (const float*)d_in[2];
    const float* sbf   = (const float*)d_in[3];
    const int*   eidx  = (const int*)d_in[4];
    const int*   l_idx = (const int*)d_in[5];
    const int*   k_idx = (const int*)d_in[6];
    const int*   batch = (const int*)d_in[7];
    const float* W_e1a = (const float*)d_in[8];
    const float* b_e1a = (const float*)d_in[9];
    const float* W_e1b = (const float*)d_in[10];
    const float* b_e1b = (const float*)d_in[11];
    const float* W_e2a = (const float*)d_in[12];
    const float* b_e2a = (const float*)d_in[13];
    const float* W_e2b = (const float*)d_in[14];
    const float* b_e2b = (const float*)d_in[15];
    const float* W_na  = (const float*)d_in[16];
    const float* b_na  = (const float*)d_in[17];
    const float* W_nb  = (const float*)d_in[18];
    const float* b_nb  = (const float*)d_in[19];
    const float* W_oa  = (const float*)d_in[20];
    const float* b_oa  = (const float*)d_in[21];
    const float* W_ob  = (const float*)d_in[22];
    const float* b_ob  = (const float*)d_in[23];

    const int* src = eidx;
    const int* dst = eidx + Ee;

    const size_t NHb = (size_t)Nn * Hh * sizeof(unsigned short);
    char* w = (char*)d_ws;
    unsigned short* hb   = (unsigned short*)w; w += NHb;
    unsigned short* P1a  = (unsigned short*)w; w += NHb;
    unsigned short* P1b  = (unsigned short*)w; w += NHb;
    unsigned short* Z1a  = (unsigned short*)w; w += NHb;
    unsigned short* Z1b  = (unsigned short*)w; w += NHb;
    unsigned short* Z2   = (unsigned short*)w; w += NHb;
    unsigned short* Rb   = (unsigned short*)w; w += NHb;
    unsigned short* P2all = (unsigned short*)w; w += 3 * NHb;
    float* pooled = (float*)w; w += (size_t)Gg * Hh * sizeof(float);
    float* cntg   = (float*)w; w += (size_t)Gg * sizeof(float);
    unsigned short* qrec = (unsigned short*)w; w += (size_t)Qq * 16 * sizeof(unsigned short);
    int*   srcs_e = (int*)w;   w += (size_t)Ee * sizeof(int);
    unsigned* estage = (unsigned*)w; w += (size_t)Ee * sizeof(unsigned);
    int*   hist_e = (int*)w;   w += (size_t)Nn * sizeof(int);   // hist_e+hist_q contiguous
    int*   hist_q = (int*)w;   w += (size_t)Nn * sizeof(int);
    int*   cur_e  = (int*)w;   w += (size_t)Nn * sizeof(int);
    int*   cur_q  = (int*)w;   w += (size_t)Nn * sizeof(int);
    int*   ebcur  = (int*)w;   w += (size_t)NBUK * sizeof(int);
    int*   bsum   = (int*)w;   w += 128 * sizeof(int);
    unsigned short* wbuf = (unsigned short*)w;                  // 3 x 135168 bf16

    const size_t LSTRIDE = 135168;

    // --- preprocessing: fused counting sorts (edges by dst, quads by k_idx) ---
    hipMemsetAsync(hist_e, 0, 2 * (size_t)Nn * sizeof(int), stream);
    k_hist2<<<(Qq + 255) / 256, 256, 0, stream>>>(dst, k_idx, hist_e, hist_q);
    {
        dim3 g(NSCB, 2);
        k_scanA2<<<g, 1024, 0, stream>>>(hist_e, hist_q, cur_e, cur_q, bsum);
        k_scanB2<<<2, 64, 0, stream>>>(bsum);
        k_scanC2<<<g, 1024, 0, stream>>>(cur_e, cur_q, bsum);
    }
    k_bukinit<<<(NBUK + 255) / 256, 256, 0, stream>>>(cur_e, ebcur);
    k_scatter_both<<<(Qq + 255) / 256, 256, 0, stream>>>(dst, src, k_idx, l_idx,
        cbf, sbf, ebcur, cur_q, estage, qrec);
    k_finalize<<<NBUK, 256, 0, stream>>>(estage, cur_e, hist_e, srcs_e);

    {
        dim3 g((135168 + 255) / 256, 3);
        k_wtall<<<g, 256, 0, stream>>>(W_e1a, W_e1b, W_e2a, W_e2b, W_na, W_nb, wbuf);
    }
    k_pre0<<<NB64, 256, 0, stream>>>(x, rbf, wbuf, hb, P1a, Z1a, P2all);

    unsigned short* P1s[2] = { P1a, P1b };
    unsigned short* Z1s[2] = { Z1a, Z1b };
    for (int p = 0; p < 3; ++p) {
        const unsigned short* wb = wbuf + p * LSTRIDE;
        const unsigned short* wbn = wbuf + ((p + 1) % 3) * LSTRIDE;
        int c = p & 1;
        k_quadagg<<<Nn / 16, 256, 0, stream>>>(P1s[c],
            P2all + (size_t)p * Nn * 128, qrec, cur_q, hist_q,
            W_e1a + (size_t)p * 146 * 128, b_e1a + (size_t)p * 128, Rb);
        k_agg2z<<<NB64, 256, 0, stream>>>(Rb, hist_q, wb, b_e1b + (size_t)p * 128, Z2);
        k_edgeagg<<<Nn / 16, 256, 0, stream>>>(Z1s[c], Z2, srcs_e, cur_e, hist_e,
            b_e2a + (size_t)p * 128, Rb);
        if (p < 2)
            k_nodeNew<0><<<NB64, 256, 0, stream>>>(Rb, hist_e, wb,
                b_e2b + (size_t)p * 128, b_na + (size_t)p * 128, b_nb + (size_t)p * 128,
                hb, wbn, P1s[c ^ 1], Z1s[c ^ 1]);
        else
            k_nodeNew<1><<<NB64, 256, 0, stream>>>(Rb, hist_e, wb,
                b_e2b + (size_t)p * 128, b_na + (size_t)p * 128, b_nb + (size_t)p * 128,
                hb, wbn, P1s[c ^ 1], Z1s[c ^ 1]);
    }
    hipMemsetAsync(pooled, 0, (size_t)(Gg * Hh + Gg) * sizeof(float), stream);
    k_pool<<<(Nn + 195) / 196, 256, 0, stream>>>(hb, batch, pooled, cntg);
    k_final<<<Gg, 128, 0, stream>>>(pooled, cntg, W_oa, b_oa, W_ob, b_ob, (float*)d_out);
}

// Round 14
// 531.032 us; speedup vs baseline: 1.0671x; 1.0671x over previous
//
#include <hip/hip_runtime.h>

constexpr int Nn = 50000;
constexpr int Ee = 800000;
constexpr int Qq = 2000000;
constexpr int Gg = 64;
constexpr int Hh = 128;
constexpr int NB64 = (Nn + 63) / 64;
constexpr int NSCB = (Nn + 1023) / 1024;   // 49 scan blocks

typedef short bf16x8 __attribute__((ext_vector_type(8)));
typedef float f32x4  __attribute__((ext_vector_type(4)));

__device__ __forceinline__ unsigned short f2bf(float f) {
    unsigned u = __builtin_bit_cast(unsigned, f);
    u += 0x7FFFu + ((u >> 16) & 1u);
    return (unsigned short)(u >> 16);
}
__device__ __forceinline__ float bf2f(unsigned short s) {
    unsigned u = ((unsigned)s) << 16;
    return __builtin_bit_cast(float, u);
}

// ---------------- fused histograms (edges by dst, quads by k_idx) ----------------
__global__ void k_hist2(const int* __restrict__ dst, const int* __restrict__ kidx,
                        int* __restrict__ hist_e, int* __restrict__ hist_q) {
    int i = blockIdx.x * blockDim.x + threadIdx.x;
    if (i < Ee) atomicAdd(&hist_e[dst[i]], 1);
    if (i < Qq) { int v = kidx[i]; if (v < Nn) atomicAdd(&hist_q[v], 1); }
}

// ---------------- hierarchical exclusive scan, 2 arrays via blockIdx.y ----------------
__global__ __launch_bounds__(1024) void k_scanA2(const int* __restrict__ he,
                                                 const int* __restrict__ hq,
                                                 int* __restrict__ ce, int* __restrict__ cq,
                                                 int* __restrict__ bs) {
    __shared__ int s[1024];
    const int* h = blockIdx.y ? hq : he;
    int* c = blockIdx.y ? cq : ce;
    int* b = bs + blockIdx.y * 64;
    const int tid = threadIdx.x;
    int i = blockIdx.x * 1024 + tid;
    int v = (i < Nn) ? h[i] : 0;
    s[tid] = v;
    __syncthreads();
    for (int off = 1; off < 1024; off <<= 1) {
        int t = (tid >= off) ? s[tid - off] : 0;
        __syncthreads();
        s[tid] += t;
        __syncthreads();
    }
    if (i < Nn) c[i] = s[tid] - v;
    if (tid == 1023) b[blockIdx.x] = s[1023];
}
__global__ void k_scanB2(int* __restrict__ bs) {
    __shared__ int s[64];
    int* b = bs + blockIdx.x * 64;
    const int tid = threadIdx.x;
    int v = (tid < NSCB) ? b[tid] : 0;
    s[tid] = v;
    __syncthreads();
    for (int off = 1; off < 64; off <<= 1) {
        int t = (tid >= off) ? s[tid - off] : 0;
        __syncthreads();
        s[tid] += t;
        __syncthreads();
    }
    if (tid < NSCB) b[tid] = s[tid] - v;
}
__global__ __launch_bounds__(1024) void k_scanC2(int* __restrict__ ce, int* __restrict__ cq,
                                                 const int* __restrict__ bs) {
    int* c = blockIdx.y ? cq : ce;
    const int* b = bs + blockIdx.y * 64;
    int i = blockIdx.x * 1024 + threadIdx.x;
    if (i < Nn) c[i] += b[blockIdx.x];
}

// ---------------- fused scatter: edges (src) + quads (packed 32B rec) ----------------
// Per-node cursors (50K addresses, ~16 hits each) — low contention. Do NOT bucket:
// fewer cursors = more same-address serialization (r13 lesson).
__global__ void k_scatter_both(const int* __restrict__ dst, const int* __restrict__ src,
                               const int* __restrict__ kidx, const int* __restrict__ lidx,
                               const float* __restrict__ cbf, const float* __restrict__ sbf,
                               int* __restrict__ cur_e, int* __restrict__ cur_q,
                               int* __restrict__ srcs, unsigned short* __restrict__ qrec) {
    int i = blockIdx.x * blockDim.x + threadIdx.x;
    if (i < Ee) {
        int p = atomicAdd(&cur_e[dst[i]], 1);
        srcs[p] = src[i];
    }
    if (i < Qq) {
        int v = kidx[i];
        if (v < Nn) {
            int p = atomicAdd(&cur_q[v], 1);
            unsigned short rec[16];
            ((int*)rec)[0] = lidx[i];
#pragma unroll
            for (int k = 0; k < 6; ++k) rec[2 + k] = f2bf(cbf[(size_t)i * 6 + k]);
#pragma unroll
            for (int k = 0; k < 6; ++k) rec[8 + k] = f2bf(sbf[(size_t)i * 6 + k]);
            rec[14] = 0; rec[15] = 0;
            *(uint4*)&qrec[(size_t)p * 16]     = *(uint4*)&rec[0];
            *(uint4*)&qrec[(size_t)p * 16 + 8] = *(uint4*)&rec[8];
        }
    }
}

// ---------------- fused per-layer weight transpose to bf16 ----------------
// per-layer slice: [0)Wq1t[128][128] [16384)Wp2t[128][32] [20480)We1bt[128][128]
// [36864)We2at[128][256] [69632)We2bt[128][128] [86016)Wnat[128][256] [118784)Wnbt[128][128]
__global__ void k_wtall(const float* __restrict__ We1a0, const float* __restrict__ We1b0,
                        const float* __restrict__ We2a0, const float* __restrict__ We2b0,
                        const float* __restrict__ Wna0,  const float* __restrict__ Wnb0,
                        unsigned short* __restrict__ wbuf) {
    int idx = blockIdx.x * blockDim.x + threadIdx.x;
    if (idx >= 135168) return;
    const int p = blockIdx.y;
    const float* We1a = We1a0 + (size_t)p * 146 * 128;
    const float* We1b = We1b0 + (size_t)p * 128 * 128;
    const float* We2a = We2a0 + (size_t)p * 256 * 128;
    const float* We2b = We2b0 + (size_t)p * 128 * 128;
    const float* Wna  = Wna0  + (size_t)p * 256 * 128;
    const float* Wnb  = Wnb0  + (size_t)p * 128 * 128;
    unsigned short* base = wbuf + (size_t)p * 135168;
    const float* src; int K, Kp, loc;
    if (idx < 16384)       { src = We1a;             K = 128; Kp = 128; loc = idx; }
    else if (idx < 20480)  { src = We1a + 128 * 128; K = 6;   Kp = 32;  loc = idx - 16384; }
    else if (idx < 36864)  { src = We1b;             K = 128; Kp = 128; loc = idx - 20480; }
    else if (idx < 69632)  { src = We2a;             K = 256; Kp = 256; loc = idx - 36864; }
    else if (idx < 86016)  { src = We2b;             K = 128; Kp = 128; loc = idx - 69632; }
    else if (idx < 118784) { src = Wna;              K = 256; Kp = 256; loc = idx - 86016; }
    else                   { src = Wnb;              K = 128; Kp = 128; loc = idx - 118784; }
    int n = loc / Kp, k = loc - n * Kp;
    base[idx] = (k < K) ? f2bf(src[(size_t)k * 128 + n]) : (unsigned short)0;
}

// ---------------- GEMM building blocks ----------------
__device__ __forceinline__ void zacc(f32x4 acc[4][2]) {
#pragma unroll
    for (int rt = 0; rt < 4; ++rt)
#pragma unroll
        for (int ct = 0; ct < 2; ++ct)
            acc[rt][ct] = (f32x4){0.f, 0.f, 0.f, 0.f};
}

template<int KK, int SA, int KP>
__device__ __forceinline__ void gemm64(const unsigned short* A,
                                       const unsigned short* __restrict__ Wt,
                                       int k_off, f32x4 acc[4][2]) {
    const int tid = threadIdx.x;
    const int lane = tid & 63;
    const int nb = (tid >> 6) * 32;
    const int rA = lane & 15;
    const int kg = lane >> 4;
#pragma unroll
    for (int ks = 0; ks < KK / 32; ++ks) {
        const int ka = ks * 32 + kg * 8;
        const int kb = k_off + ka;
        bf16x8 b0 = *(const bf16x8*)&Wt[(size_t)(nb + rA) * KP + kb];
        bf16x8 b1 = *(const bf16x8*)&Wt[(size_t)(nb + 16 + rA) * KP + kb];
#pragma unroll
        for (int rt = 0; rt < 4; ++rt) {
            bf16x8 a = *(const bf16x8*)&A[(rt * 16 + rA) * SA + ka];
            acc[rt][0] = __builtin_amdgcn_mfma_f32_16x16x32_bf16(a, b0, acc[rt][0], 0, 0, 0);
            acc[rt][1] = __builtin_amdgcn_mfma_f32_16x16x32_bf16(a, b1, acc[rt][1], 0, 0, 0);
        }
    }
}

__device__ __forceinline__ void store_acc(const f32x4 acc[4][2], unsigned short* out,
                                          int n0, int nmax) {
    const int tid = threadIdx.x;
    const int lane = tid & 63;
    const int nb = (tid >> 6) * 32;
    const int rA = lane & 15, kg = lane >> 4;
#pragma unroll
    for (int rt = 0; rt < 4; ++rt)
#pragma unroll
        for (int ct = 0; ct < 2; ++ct) {
            int col = nb + ct * 16 + rA;
#pragma unroll
            for (int i = 0; i < 4; ++i) {
                int n = n0 + rt * 16 + kg * 4 + i;
                if (n < nmax) out[(size_t)n * 128 + col] = f2bf(acc[rt][ct][i]);
            }
        }
}

// ---------------- k_pre0: hb=bf16(x); P1=h*Wq1(l0); Z1=h*We2a(l0)[:128]; P2(l0..l2) -----
__global__ __launch_bounds__(256) void k_pre0(
    const float* __restrict__ x, const float* __restrict__ rbf,
    const unsigned short* __restrict__ wbuf,
    unsigned short* __restrict__ hb,
    unsigned short* __restrict__ P1, unsigned short* __restrict__ Z1,
    unsigned short* __restrict__ P2all)
{
    __shared__ unsigned short TA[64 * 136];
    const int m0 = blockIdx.x * 64;
    const int tid = threadIdx.x;
    for (int i = tid; i < 64 * 32; i += 256) {
        int row = i >> 5, c = i & 31;
        int n = m0 + row;
        int nc = min(n, Nn - 1);
        float4 v = *(const float4*)&x[(size_t)nc * 128 + c * 4];
        ushort4 o;
        o.x = f2bf(v.x); o.y = f2bf(v.y); o.z = f2bf(v.z); o.w = f2bf(v.w);
        *(ushort4*)&TA[row * 136 + c * 4] = o;
        if (n < Nn) *(ushort4*)&hb[(size_t)n * 128 + c * 4] = o;
    }
    __syncthreads();
    f32x4 acc[4][2];
    zacc(acc);
    gemm64<128, 136, 128>(TA, wbuf, 0, acc);
    store_acc(acc, P1, m0, Nn);
    zacc(acc);
    gemm64<128, 136, 256>(TA, wbuf + 36864, 0, acc);
    store_acc(acc, Z1, m0, Nn);
    __syncthreads();
    for (int i = tid; i < 64 * 32; i += 256) {
        int row = i >> 5, c = i & 31;
        int nc = min(m0 + row, Nn - 1);
        float v = (c < 6) ? rbf[(size_t)nc * 6 + c] : 0.f;
        TA[row * 136 + c] = f2bf(v);
    }
    __syncthreads();
    for (int p = 0; p < 3; ++p) {
        zacc(acc);
        gemm64<32, 136, 32>(TA, wbuf + (size_t)p * 135168 + 16384, 0, acc);
        store_acc(acc, P2all + (size_t)p * Nn * 128, m0, Nn);
    }
}

// ---------------- k_quadagg: CSR owner-computes quad reduction (zero atomics) --------
__global__ __launch_bounds__(256) void k_quadagg(
    const unsigned short* __restrict__ P1, const unsigned short* __restrict__ P2,
    const unsigned short* __restrict__ qrec,
    const int* __restrict__ rowend, const int* __restrict__ rowcnt,
    const float* __restrict__ We1a_raw, const float* __restrict__ b_e1a,
    unsigned short* __restrict__ Rb)
{
    __shared__ float W34[12 * 128];
    __shared__ float bia[128];
    const int tid = threadIdx.x;
    for (int i = tid; i < 12 * 128; i += 256) W34[i] = We1a_raw[134 * 128 + i];
    if (tid < 128) bia[tid] = b_e1a[tid];
    __syncthreads();
    const int nd = tid >> 4;
    const int c0 = (tid & 15) * 8;
    const int n = blockIdx.x * 16 + nd;
    const int end = rowend[n];
    const int beg = end - rowcnt[n];
    float base[8];
    {
        uint4 p2v = *(const uint4*)&P2[(size_t)n * 128 + c0];
        const unsigned short* pp = (const unsigned short*)&p2v;
#pragma unroll
        for (int k = 0; k < 8; ++k) base[k] = bia[c0 + k] + bf2f(pp[k]);
    }
    float acc[8];
#pragma unroll
    for (int k = 0; k < 8; ++k) acc[k] = 0.f;
    for (int e = beg; e < end; ++e) {
        uint4 r0 = *(const uint4*)&qrec[(size_t)e * 16];
        uint4 r1 = *(const uint4*)&qrec[(size_t)e * 16 + 8];
        int l = ((const int*)&r0)[0];
        uint4 a = *(const uint4*)&P1[(size_t)l * 128 + c0];
        const unsigned short* q0 = (const unsigned short*)&r0;
        const unsigned short* q1 = (const unsigned short*)&r1;
        float qv[12] = {bf2f(q0[2]), bf2f(q0[3]), bf2f(q0[4]), bf2f(q0[5]),
                        bf2f(q0[6]), bf2f(q0[7]), bf2f(q1[0]), bf2f(q1[1]),
                        bf2f(q1[2]), bf2f(q1[3]), bf2f(q1[4]), bf2f(q1[5])};
        const unsigned short* ap = (const unsigned short*)&a;
        float t[8];
#pragma unroll
        for (int k = 0; k < 8; ++k) t[k] = base[k] + bf2f(ap[k]);
#pragma unroll
        for (int kk = 0; kk < 12; ++kk) {
            float q_ = qv[kk];
#pragma unroll
            for (int k = 0; k < 8; ++k)
                t[k] = fmaf(q_, W34[kk * 128 + c0 + k], t[k]);
        }
#pragma unroll
        for (int k = 0; k < 8; ++k) acc[k] += fmaxf(t[k], 0.f);
    }
    unsigned short ov[8];
#pragma unroll
    for (int k = 0; k < 8; ++k) ov[k] = f2bf(acc[k]);
    *(uint4*)&Rb[(size_t)n * 128 + c0] = *(uint4*)ov;
}

// ---------------- k_edgeagg: CSR owner-computes edge reduction, 4-way ILP --------
__global__ __launch_bounds__(256) void k_edgeagg(
    const unsigned short* __restrict__ Z1, const unsigned short* __restrict__ Z2,
    const int* __restrict__ srcs,
    const int* __restrict__ rowend, const int* __restrict__ rowcnt,
    const float* __restrict__ b_e2a,
    unsigned short* __restrict__ Rb)
{
    const int tid = threadIdx.x;
    const int nd = tid >> 4;
    const int c0 = (tid & 15) * 8;
    const int n = blockIdx.x * 16 + nd;
    const int end = rowend[n];
    const int beg = end - rowcnt[n];
    float z2b[8];
    {
        uint4 zv = *(const uint4*)&Z2[(size_t)n * 128 + c0];
        const unsigned short* zp = (const unsigned short*)&zv;
        float4 b0 = *(const float4*)&b_e2a[c0];
        float4 b1 = *(const float4*)&b_e2a[c0 + 4];
        z2b[0] = b0.x + bf2f(zp[0]); z2b[1] = b0.y + bf2f(zp[1]);
        z2b[2] = b0.z + bf2f(zp[2]); z2b[3] = b0.w + bf2f(zp[3]);
        z2b[4] = b1.x + bf2f(zp[4]); z2b[5] = b1.y + bf2f(zp[5]);
        z2b[6] = b1.z + bf2f(zp[6]); z2b[7] = b1.w + bf2f(zp[7]);
    }
    float acc[8];
#pragma unroll
    for (int k = 0; k < 8; ++k) acc[k] = 0.f;
    int e = beg;
    for (; e + 4 <= end; e += 4) {           // 4-way ILP on the gather
        int s0 = srcs[e], s1 = srcs[e + 1], s2 = srcs[e + 2], s3 = srcs[e + 3];
        uint4 a0 = *(const uint4*)&Z1[(size_t)s0 * 128 + c0];
        uint4 a1 = *(const uint4*)&Z1[(size_t)s1 * 128 + c0];
        uint4 a2 = *(const uint4*)&Z1[(size_t)s2 * 128 + c0];
        uint4 a3 = *(const uint4*)&Z1[(size_t)s3 * 128 + c0];
        const unsigned short* p0 = (const unsigned short*)&a0;
        const unsigned short* p1 = (const unsigned short*)&a1;
        const unsigned short* p2 = (const unsigned short*)&a2;
        const unsigned short* p3 = (const unsigned short*)&a3;
#pragma unroll
        for (int k = 0; k < 8; ++k) acc[k] += fmaxf(z2b[k] + bf2f(p0[k]), 0.f);
#pragma unroll
        for (int k = 0; k < 8; ++k) acc[k] += fmaxf(z2b[k] + bf2f(p1[k]), 0.f);
#pragma unroll
        for (int k = 0; k < 8; ++k) acc[k] += fmaxf(z2b[k] + bf2f(p2[k]), 0.f);
#pragma unroll
        for (int k = 0; k < 8; ++k) acc[k] += fmaxf(z2b[k] + bf2f(p3[k]), 0.f);
    }
    for (; e + 2 <= end; e += 2) {
        int s0 = srcs[e], s1 = srcs[e + 1];
        uint4 a0 = *(const uint4*)&Z1[(size_t)s0 * 128 + c0];
        uint4 a1 = *(const uint4*)&Z1[(size_t)s1 * 128 + c0];
        const unsigned short* p0 = (const unsigned short*)&a0;
        const unsigned short* p1 = (const unsigned short*)&a1;
#pragma unroll
        for (int k = 0; k < 8; ++k) acc[k] += fmaxf(z2b[k] + bf2f(p0[k]), 0.f);
#pragma unroll
        for (int k = 0; k < 8; ++k) acc[k] += fmaxf(z2b[k] + bf2f(p1[k]), 0.f);
    }
    if (e < end) {
        int s0 = srcs[e];
        uint4 a0 = *(const uint4*)&Z1[(size_t)s0 * 128 + c0];
        const unsigned short* p0 = (const unsigned short*)&a0;
#pragma unroll
        for (int k = 0; k < 8; ++k) acc[k] += fmaxf(z2b[k] + bf2f(p0[k]), 0.f);
    }
    unsigned short ov[8];
#pragma unroll
    for (int k = 0; k < 8; ++k) ov[k] = f2bf(acc[k]);
    *(uint4*)&Rb[(size_t)n * 128 + c0] = *(uint4*)ov;
}

// ---------------- k_agg2z: T = Rq*We1b + cntq*b_e1b ; Z2 = T*We2a[128:256] ----------------
__global__ __launch_bounds__(256) void k_agg2z(
    const unsigned short* __restrict__ Rb, const int* __restrict__ cntq,
    const unsigned short* __restrict__ wb, const float* __restrict__ b_e1b,
    unsigned short* __restrict__ Z2)
{
    __shared__ unsigned short L[64 * 136];
    __shared__ int rc[64];
    const int m0 = blockIdx.x * 64;
    const int tid = threadIdx.x;
    const unsigned short* We1bt = wb + 20480;
    const unsigned short* We2at = wb + 36864;
    if (tid < 64) rc[tid] = (m0 + tid < Nn) ? cntq[m0 + tid] : 0;
    for (int i = tid; i < 64 * 16; i += 256) {
        int row = i >> 4, ch = i & 15;
        int n = min(m0 + row, Nn - 1);
        *(uint4*)&L[row * 136 + ch * 8] = *(const uint4*)&Rb[(size_t)n * 128 + ch * 8];
    }
    __syncthreads();
    f32x4 acc[4][2];
    zacc(acc);
    gemm64<128, 136, 128>(L, We1bt, 0, acc);
    __syncthreads();
    {
        const int lane = tid & 63;
        const int nb = (tid >> 6) * 32;
        const int rA = lane & 15, kg = lane >> 4;
#pragma unroll
        for (int rt = 0; rt < 4; ++rt)
#pragma unroll
            for (int ct = 0; ct < 2; ++ct) {
                int col = nb + ct * 16 + rA;
                float bias = b_e1b[col];
#pragma unroll
                for (int i = 0; i < 4; ++i) {
                    int row = rt * 16 + kg * 4 + i;
                    L[row * 136 + col] = f2bf(acc[rt][ct][i] + (float)rc[row] * bias);
                }
            }
    }
    __syncthreads();
    zacc(acc);
    gemm64<128, 136, 256>(L, We2at, 128, acc);
    store_acc(acc, Z2, m0, Nn);
}

// ---------------- k_nodeNew: in-place h update + next-layer P1/Z1 tail ----------------
template<int LAST>
__global__ __launch_bounds__(256) void k_nodeNew(
    const unsigned short* __restrict__ Rb, const int* __restrict__ deg,
    const unsigned short* __restrict__ wb,
    const float* __restrict__ b_e2b, const float* __restrict__ b_na,
    const float* __restrict__ b_nb,
    unsigned short* __restrict__ hb,
    const unsigned short* __restrict__ wbn,
    unsigned short* __restrict__ P1n, unsigned short* __restrict__ Z1n)
{
    __shared__ unsigned short L[64 * 136];
    __shared__ int rc[64];
    const int m0 = blockIdx.x * 64;
    const int tid = threadIdx.x;
    const unsigned short* We2bt = wb + 69632;
    const unsigned short* Wnat  = wb + 86016;
    const unsigned short* Wnbt  = wb + 118784;
    const int lane = tid & 63;
    const int nb = (tid >> 6) * 32;
    const int rA = lane & 15, kg = lane >> 4;
    if (tid < 64) rc[tid] = (m0 + tid < Nn) ? deg[m0 + tid] : 0;
    for (int i = tid; i < 64 * 16; i += 256) {
        int row = i >> 4, ch = i & 15;
        int n = min(m0 + row, Nn - 1);
        *(uint4*)&L[row * 136 + ch * 8] = *(const uint4*)&Rb[(size_t)n * 128 + ch * 8];
    }
    __syncthreads();
    f32x4 acc[4][2];
    zacc(acc);
    gemm64<128, 136, 128>(L, We2bt, 0, acc);     // U = Re*We2b
    __syncthreads();
#pragma unroll
    for (int rt = 0; rt < 4; ++rt)
#pragma unroll
        for (int ct = 0; ct < 2; ++ct) {
            int col = nb + ct * 16 + rA;
            float bias = b_e2b[col];
#pragma unroll
            for (int i = 0; i < 4; ++i) {
                int row = rt * 16 + kg * 4 + i;
                L[row * 136 + col] = f2bf(acc[rt][ct][i] + (float)rc[row] * bias);
            }
        }
    __syncthreads();
    f32x4 acc2[4][2];
    zacc(acc2);
    gemm64<128, 136, 256>(L, Wnat, 128, acc2);   // V = U*Wbot_n
    __syncthreads();
    for (int i = tid; i < 64 * 16; i += 256) {
        int row = i >> 4, ch = i & 15;
        int n = min(m0 + row, Nn - 1);
        *(uint4*)&L[row * 136 + ch * 8] = *(const uint4*)&hb[(size_t)n * 128 + ch * 8];
    }
    __syncthreads();
    gemm64<128, 136, 256>(L, Wnat, 0, acc2);     // V += h*Wtop_n
    __syncthreads();
#pragma unroll
    for (int rt = 0; rt < 4; ++rt)
#pragma unroll
        for (int ct = 0; ct < 2; ++ct) {
            int col = nb + ct * 16 + rA;
            float bias = b_na[col];
#pragma unroll
            for (int i = 0; i < 4; ++i) {
                int row = rt * 16 + kg * 4 + i;
                L[row * 136 + col] = f2bf(fmaxf(acc2[rt][ct][i] + bias, 0.f));
            }
        }
    __syncthreads();
    zacc(acc);
    gemm64<128, 136, 128>(L, Wnbt, 0, acc);      // h' = hidden*Wnb
    __syncthreads();                             // all L reads done before overwrite
#pragma unroll
    for (int rt = 0; rt < 4; ++rt)
#pragma unroll
        for (int ct = 0; ct < 2; ++ct) {
            int col = nb + ct * 16 + rA;
            float bias = b_nb[col];
#pragma unroll
            for (int i = 0; i < 4; ++i) {
                int row = rt * 16 + kg * 4 + i;
                int n = m0 + row;
                unsigned short hv = f2bf(acc[rt][ct][i] + bias);
                if (n < Nn) hb[(size_t)n * 128 + col] = hv;
                if (!LAST) L[row * 136 + col] = hv;
            }
        }
    if (!LAST) {
        __syncthreads();
        // tail: next layer's P1 = h'*Wq1n ; Z1 = h'*We2an[:128]  (h' already in LDS)
        zacc(acc);
        gemm64<128, 136, 128>(L, wbn, 0, acc);
        store_acc(acc, P1n, m0, Nn);
        zacc(acc);
        gemm64<128, 136, 256>(L, wbn + 36864, 0, acc);
        store_acc(acc, Z1n, m0, Nn);
    }
}

// ---------------- global mean pool: run-length segmented reduction ----------------
__global__ __launch_bounds__(256) void k_pool(const unsigned short* __restrict__ hb,
                                              const int* __restrict__ batch,
                                              float* __restrict__ pooled,
                                              float* __restrict__ cntg) {
    __shared__ int bseg[200];
    constexpr int CH = 196;
    const int start = blockIdx.x * CH;
    const int end = min(start + CH, Nn);
    if (start >= end) return;
    const int tid = threadIdx.x;
    for (int i = tid; i < end - start; i += 256) bseg[i] = batch[start + i];
    __syncthreads();
    const int j = tid & 127;
    const int rh = tid >> 7;
    float acc = 0.f, cacc = 0.f;
    int cur = -1;
    for (int n = start + rh; n < end; n += 2) {
        int g = bseg[n - start];
        if (g != cur) {
            if (cur >= 0) {
                atomicAdd(&pooled[cur * Hh + j], acc);
                if (j == 0) atomicAdd(&cntg[cur], cacc);
            }
            cur = g; acc = 0.f; cacc = 0.f;
        }
        acc += bf2f(hb[(size_t)n * Hh + j]);
        cacc += 1.f;
    }
    if (cur >= 0) {
        atomicAdd(&pooled[cur * Hh + j], acc);
        if (j == 0) atomicAdd(&cntg[cur], cacc);
    }
}

// ---------------- final per-graph MLP ----------------
__global__ __launch_bounds__(128) void k_final(
    const float* __restrict__ pooled, const float* __restrict__ cntg,
    const float* __restrict__ Woa, const float* __restrict__ boa,
    const float* __restrict__ Wob, const float* __restrict__ bob,
    float* __restrict__ out)
{
    __shared__ float p[128];
    __shared__ float t[128];
    __shared__ float red[128];
    const int g = blockIdx.x;
    const int j = threadIdx.x;
    float c = fmaxf(cntg[g], 1.f);
    p[j] = fmaxf(pooled[g * Hh + j] / c, 0.f);
    __syncthreads();
    float acc = boa[j];
    for (int d = 0; d < Hh; ++d) acc = fmaf(p[d], Woa[d * Hh + j], acc);
    t[j] = fmaxf(acc, 0.f);
    __syncthreads();
    red[j] = t[j] * Wob[j];
    __syncthreads();
    for (int s = 64; s > 0; s >>= 1) {
        if (j < s) red[j] += red[j + s];
        __syncthreads();
    }
    if (j == 0) out[g] = red[0] + bob[0];
}

extern "C" void kernel_launch(void* const* d_in, const int* in_sizes, int n_in,
                              void* d_out, int out_size, void* d_ws, size_t ws_size,
                              hipStream_t stream) {
    const float* x     = (const float*)d_in[0];
    const float* rbf   = (const float*)d_in[1];
    const float* cbf   = (const float*)d_in[2];
    const float* sbf   = (const float*)d_in[3];
    const int*   eidx  = (const int*)d_in[4];
    const int*   l_idx = (const int*)d_in[5];
    const int*   k_idx = (const int*)d_in[6];
    const int*   batch = (const int*)d_in[7];
    const float* W_e1a = (const float*)d_in[8];
    const float* b_e1a = (const float*)d_in[9];
    const float* W_e1b = (const float*)d_in[10];
    const float* b_e1b = (const float*)d_in[11];
    const float* W_e2a = (const float*)d_in[12];
    const float* b_e2a = (const float*)d_in[13];
    const float* W_e2b = (const float*)d_in[14];
    const float* b_e2b = (const float*)d_in[15];
    const float* W_na  = (const float*)d_in[16];
    const float* b_na  = (const float*)d_in[17];
    const float* W_nb  = (const float*)d_in[18];
    const float* b_nb  = (const float*)d_in[19];
    const float* W_oa  = (const float*)d_in[20];
    const float* b_oa  = (const float*)d_in[21];
    const float* W_ob  = (const float*)d_in[22];
    const float* b_ob  = (const float*)d_in[23];

    const int* src = eidx;
    const int* dst = eidx + Ee;

    const size_t NHb = (size_t)Nn * Hh * sizeof(unsigned short);
    char* w = (char*)d_ws;
    unsigned short* hb   = (unsigned short*)w; w += NHb;
    unsigned short* P1a  = (unsigned short*)w; w += NHb;
    unsigned short* P1b  = (unsigned short*)w; w += NHb;
    unsigned short* Z1a  = (unsigned short*)w; w += NHb;
    unsigned short* Z1b  = (unsigned short*)w; w += NHb;
    unsigned short* Z2   = (unsigned short*)w; w += NHb;
    unsigned short* Rb   = (unsigned short*)w; w += NHb;
    unsigned short* P2all = (unsigned short*)w; w += 3 * NHb;
    float* pooled = (float*)w; w += (size_t)Gg * Hh * sizeof(float);
    float* cntg   = (float*)w; w += (size_t)Gg * sizeof(float);
    unsigned short* qrec = (unsigned short*)w; w += (size_t)Qq * 16 * sizeof(unsigned short);
    int*   srcs_e = (int*)w;   w += (size_t)Ee * sizeof(int);
    int*   hist_e = (int*)w;   w += (size_t)Nn * sizeof(int);   // hist_e+hist_q contiguous
    int*   hist_q = (int*)w;   w += (size_t)Nn * sizeof(int);
    int*   cur_e  = (int*)w;   w += (size_t)Nn * sizeof(int);
    int*   cur_q  = (int*)w;   w += (size_t)Nn * sizeof(int);
    int*   bsum   = (int*)w;   w += 128 * sizeof(int);
    unsigned short* wbuf = (unsigned short*)w;                  // 3 x 135168 bf16

    const size_t LSTRIDE = 135168;

    // --- preprocessing: fused counting sorts (edges by dst, quads by k_idx) ---
    hipMemsetAsync(hist_e, 0, 2 * (size_t)Nn * sizeof(int), stream);
    k_hist2<<<(Qq + 255) / 256, 256, 0, stream>>>(dst, k_idx, hist_e, hist_q);
    {
        dim3 g(NSCB, 2);
        k_scanA2<<<g, 1024, 0, stream>>>(hist_e, hist_q, cur_e, cur_q, bsum);
        k_scanB2<<<2, 64, 0, stream>>>(bsum);
        k_scanC2<<<g, 1024, 0, stream>>>(cur_e, cur_q, bsum);
    }
    k_scatter_both<<<(Qq + 255) / 256, 256, 0, stream>>>(dst, src, k_idx, l_idx,
        cbf, sbf, cur_e, cur_q, srcs_e, qrec);

    {
        dim3 g((135168 + 255) / 256, 3);
        k_wtall<<<g, 256, 0, stream>>>(W_e1a, W_e1b, W_e2a, W_e2b, W_na, W_nb, wbuf);
    }
    k_pre0<<<NB64, 256, 0, stream>>>(x, rbf, wbuf, hb, P1a, Z1a, P2all);

    unsigned short* P1s[2] = { P1a, P1b };
    unsigned short* Z1s[2] = { Z1a, Z1b };
    for (int p = 0; p < 3; ++p) {
        const unsigned short* wb = wbuf + p * LSTRIDE;
        const unsigned short* wbn = wbuf + ((p + 1) % 3) * LSTRIDE;
        int c = p & 1;
        k_quadagg<<<Nn / 16, 256, 0, stream>>>(P1s[c],
            P2all + (size_t)p * Nn * 128, qrec, cur_q, hist_q,
            W_e1a + (size_t)p * 146 * 128, b_e1a + (size_t)p * 128, Rb);
        k_agg2z<<<NB64, 256, 0, stream>>>(Rb, hist_q, wb, b_e1b + (size_t)p * 128, Z2);
        k_edgeagg<<<Nn / 16, 256, 0, stream>>>(Z1s[c], Z2, srcs_e, cur_e, hist_e,
            b_e2a + (size_t)p * 128, Rb);
        if (p < 2)
            k_nodeNew<0><<<NB64, 256, 0, stream>>>(Rb, hist_e, wb,
                b_e2b + (size_t)p * 128, b_na + (size_t)p * 128, b_nb + (size_t)p * 128,
                hb, wbn, P1s[c ^ 1], Z1s[c ^ 1]);
        else
            k_nodeNew<1><<<NB64, 256, 0, stream>>>(Rb, hist_e, wb,
                b_e2b + (size_t)p * 128, b_na + (size_t)p * 128, b_nb + (size_t)p * 128,
                hb, wbn, P1s[c ^ 1], Z1s[c ^ 1]);
    }
    hipMemsetAsync(pooled, 0, (size_t)(Gg * Hh + Gg) * sizeof(float), stream);
    k_pool<<<(Nn + 195) / 196, 256, 0, stream>>>(hb, batch, pooled, cntg);
    k_final<<<Gg, 128, 0, stream>>>(pooled, cntg, W_oa, b_oa, W_ob, b_ob, (float*)d_out);
}